// Round 5
// baseline (84.550 us; speedup 1.0000x reference)
//
#include <hip/hip_runtime.h>
#include <math.h>

// QuantumLayer: 4 qubits, 2 layers, B=524288.
//
// z_q = P^T C_q Q ; P/Q = 10 unordered pair-products of the two 4-dim real
// product-state factors (qubits 0,1 / 2,3). C = 4x10x10 batch-uniform tensor
// from the weights, packed float4 C4[pi*10+qi] = {C0,C1,C2,C3} in d_ws.
//
// build_C4: 1 block, weights -> U(16x16 complex) -> A^q -> C4.
// qmain: 2 samples/thread, 2048 blocks. C4 read with compile-time-uniform
// indices from a __restrict__ pointer -> s_load_dwordx4 (scalar path, no LDS,
// no per-lane VMEM); inner loop is v_pk_fma_f32 with SGPR coefficient operands.
// Design rule learned R3/R4: this kernel is latency-bound -> keep VGPRs low
// (~80) and blocks plentiful; never rebuild C per block.

#define HALF_PI_F 1.57079632679489661923f

typedef float f32x2 __attribute__((ext_vector_type(2)));

__global__ __launch_bounds__(256) void build_C4(
    const float* __restrict__ weight,
    float4* __restrict__ C4g)  // 100 float4
{
    __shared__ float cw[16], sw[16];
    __shared__ float Ur[16][16], Ui[16][16];
    __shared__ float A[4][16][16];

    const int tid = threadIdx.x;
    if (tid < 16) {
        float h = 0.5f * weight[tid];
        __sincosf(h, &sw[tid], &cw[tid]);
    }
    __syncthreads();

    if (tid < 16) {
        const int col = tid;
        float re[16], im[16];
        #pragma unroll
        for (int i = 0; i < 16; ++i) { re[i] = 0.f; im[i] = 0.f; }
        re[col] = 1.f;

        #pragma unroll
        for (int layer = 0; layer < 2; ++layer) {
            #pragma unroll
            for (int q = 0; q < 4; ++q) {
                float cy = cw[layer*8 + q*2 + 0];
                float sy = sw[layer*8 + q*2 + 0];
                float cz = cw[layer*8 + q*2 + 1];
                float sz = sw[layer*8 + q*2 + 1];
                int st = 8 >> q;
                #pragma unroll
                for (int i = 0; i < 16; ++i) {
                    if (i & st) continue;
                    int j = i | st;
                    float r0 = re[i], r1 = re[j], i0 = im[i], i1 = im[j];
                    float nr0 = cy*r0 - sy*r1;
                    float nr1 = sy*r0 + cy*r1;
                    float ni0 = cy*i0 - sy*i1;
                    float ni1 = sy*i0 + cy*i1;
                    re[i] = nr0*cz + ni0*sz;
                    im[i] = ni0*cz - nr0*sz;
                    re[j] = nr1*cz - ni1*sz;
                    im[j] = ni1*cz + nr1*sz;
                }
            }
            #pragma unroll
            for (int q = 0; q < 4; ++q) {
                int cb = 8 >> q;
                int tb = 8 >> ((q + 1) & 3);
                #pragma unroll
                for (int i = 0; i < 16; ++i) {
                    if ((i & cb) && !(i & tb)) {
                        int j = i | tb;
                        float tr = re[i]; re[i] = re[j]; re[j] = tr;
                        float ti = im[i]; im[i] = im[j]; im[j] = ti;
                    }
                }
            }
        }
        #pragma unroll
        for (int i = 0; i < 16; ++i) { Ur[i][col] = re[i]; Ui[i][col] = im[i]; }
    }
    __syncthreads();

    for (int e = tid; e < 1024; e += 256) {
        int q = e >> 8, j = (e >> 4) & 15, k = e & 15;
        float sum = 0.f;
        for (int i = 0; i < 16; ++i) {
            float t = Ur[i][j]*Ur[i][k] + Ui[i][j]*Ui[i][k];
            sum += (i & (8 >> q)) ? -t : t;
        }
        A[q][j][k] = sum;
    }
    __syncthreads();

    if (tid < 100) {
        const int pu[10] = {0,0,0,0,1,1,1,2,2,3};
        const int pv[10] = {0,1,2,3,1,2,3,2,3,3};
        int pi = tid / 10, qi = tid % 10;
        int u = pu[pi], v = pv[pi], r = pu[qi], sI = pv[qi];
        int a1s[2] = {u, v}, a2s[2] = {v, u};
        int b1s[2] = {r, sI}, b2s[2] = {sI, r};
        int na = (u == v) ? 1 : 2;
        int nb = (r == sI) ? 1 : 2;
        float acc[4] = {0.f, 0.f, 0.f, 0.f};
        for (int ia = 0; ia < na; ++ia)
            for (int ib = 0; ib < nb; ++ib) {
                int j = a1s[ia]*4 + b1s[ib];
                int k = a2s[ia]*4 + b2s[ib];
                #pragma unroll
                for (int q = 0; q < 4; ++q) acc[q] += A[q][j][k];
            }
        C4g[tid] = float4{acc[0], acc[1], acc[2], acc[3]};
    }
}

__global__ __launch_bounds__(256) void qmain(
    const float* __restrict__ x,
    const float4* __restrict__ C4g,  // uniform reads -> s_load_dwordx4
    float* __restrict__ out,
    int B)
{
    const int tid = threadIdx.x;
    const int s0 = blockIdx.x * 512 + tid;
    const int s1 = s0 + 256;

    float4 xv0 = (s0 < B) ? reinterpret_cast<const float4*>(x)[s0]
                          : float4{0.f, 0.f, 0.f, 0.f};
    float4 xv1 = (s1 < B) ? reinterpret_cast<const float4*>(x)[s1]
                          : float4{0.f, 0.f, 0.f, 0.f};

    const int pu[10] = {0,0,0,0,1,1,1,2,2,3};
    const int pv[10] = {0,1,2,3,1,2,3,2,3,3};

    float P0[10], Q0[10], P1[10], Q1[10];
    {
        float xs[8] = {xv0.x, xv0.y, xv0.z, xv0.w, xv1.x, xv1.y, xv1.z, xv1.w};
        float c[8], s[8];
        #pragma unroll
        for (int q = 0; q < 8; ++q) {
            // tanh(x) = 1 - 2/(e^{2x}+1); fast-math err ~1e-6 vs 2e-2 threshold
            float e = __expf(2.f * xs[q]);
            float t = 1.f - __fdividef(2.f, e + 1.f);
            __sincosf(t * HALF_PI_F, &s[q], &c[q]);
        }
        float a0[4] = {c[0]*c[1], c[0]*s[1], s[0]*c[1], s[0]*s[1]};
        float b0[4] = {c[2]*c[3], c[2]*s[3], s[2]*c[3], s[2]*s[3]};
        float a1[4] = {c[4]*c[5], c[4]*s[5], s[4]*c[5], s[4]*s[5]};
        float b1[4] = {c[6]*c[7], c[6]*s[7], s[6]*c[7], s[6]*s[7]};
        #pragma unroll
        for (int i2 = 0; i2 < 10; ++i2) {
            P0[i2] = a0[pu[i2]] * a0[pv[i2]];
            Q0[i2] = b0[pu[i2]] * b0[pv[i2]];
            P1[i2] = a1[pu[i2]] * a1[pv[i2]];
            Q1[i2] = b1[pu[i2]] * b1[pv[i2]];
        }
    }

    f32x2 z01_0 = {0.f, 0.f}, z23_0 = {0.f, 0.f};
    f32x2 z01_1 = {0.f, 0.f}, z23_1 = {0.f, 0.f};
    #pragma unroll
    for (int pi = 0; pi < 10; ++pi) {
        f32x2 t01_0 = {0.f, 0.f}, t23_0 = {0.f, 0.f};
        f32x2 t01_1 = {0.f, 0.f}, t23_1 = {0.f, 0.f};
        #pragma unroll
        for (int qi = 0; qi < 10; ++qi) {
            float4 cv = C4g[pi*10 + qi];   // uniform -> scalar load
            f32x2 c01 = {cv.x, cv.y};
            f32x2 c23 = {cv.z, cv.w};
            f32x2 qb0 = {Q0[qi], Q0[qi]};
            f32x2 qb1 = {Q1[qi], Q1[qi]};
            t01_0 += c01 * qb0;  t23_0 += c23 * qb0;
            t01_1 += c01 * qb1;  t23_1 += c23 * qb1;
        }
        f32x2 pb0 = {P0[pi], P0[pi]};
        f32x2 pb1 = {P1[pi], P1[pi]};
        z01_0 += t01_0 * pb0;  z23_0 += t23_0 * pb0;
        z01_1 += t01_1 * pb1;  z23_1 += t23_1 * pb1;
    }

    if (s0 < B)
        reinterpret_cast<float4*>(out)[s0] =
            float4{z01_0.x, z01_0.y, z23_0.x, z23_0.y};
    if (s1 < B)
        reinterpret_cast<float4*>(out)[s1] =
            float4{z01_1.x, z01_1.y, z23_1.x, z23_1.y};
}

extern "C" void kernel_launch(void* const* d_in, const int* in_sizes, int n_in,
                              void* d_out, int out_size, void* d_ws, size_t ws_size,
                              hipStream_t stream) {
    const float* x = (const float*)d_in[0];
    const float* w = (const float*)d_in[1];
    float* out = (float*)d_out;
    float4* C4g = (float4*)d_ws;  // 100 float4 = 1600 B
    int B = in_sizes[0] / 4;

    build_C4<<<1, 256, 0, stream>>>(w, C4g);
    int grid = (B + 511) / 512;  // 2 samples/thread, 256 threads/block
    qmain<<<grid, 256, 0, stream>>>(x, C4g, out, B);
}

// Round 6
// 70.622 us; speedup vs baseline: 1.1972x; 1.1972x over previous
//
#include <hip/hip_runtime.h>
#include <math.h>

// QuantumLayer: 4 qubits, 2 layers, B=524288.
//
// z_q = P^T C_q Q ; P/Q = 10 unordered pair-products of the two 4-dim real
// product-state factors (qubits 0,1 / 2,3). C = batch-uniform tensor from the
// weights, packed float4 C4[pi*10+qi] = {C0,C1,C2,C3} in d_ws.
//
// Structure locked by rounds 1-5 evidence:
//  - two kernels (fusing the serial C-build into the wide kernel: R3, -49 us)
//  - 1 sample/thread, 2048 blocks (2/4-sample variants raise VGPRs: R4/R5 lost)
//  - scalar v_fmac chains with uniform-load coefficients (f32x2 "packed"
//    forms emitted mov-heavy code: R4/R5 lost; scalar R1/R2 won)
//  - coefficients via compile-time-uniform loads -> s_load, here merged to
//    s_load_dwordx4 by the [10][10][4] layout (the ONLY delta vs R2).

#define HALF_PI_F 1.57079632679489661923f

__global__ __launch_bounds__(256) void build_C4(
    const float* __restrict__ weight,
    float4* __restrict__ C4g)  // 100 float4: [pi][qi][q]
{
    __shared__ float cw[16], sw[16];
    __shared__ float Ur[16][16], Ui[16][16];
    __shared__ float A[4][16][16];

    const int tid = threadIdx.x;
    if (tid < 16) {
        float h = 0.5f * weight[tid];
        __sincosf(h, &sw[tid], &cw[tid]);
    }
    __syncthreads();

    if (tid < 16) {
        const int col = tid;
        float re[16], im[16];
        #pragma unroll
        for (int i = 0; i < 16; ++i) { re[i] = 0.f; im[i] = 0.f; }
        re[col] = 1.f;

        #pragma unroll
        for (int layer = 0; layer < 2; ++layer) {
            #pragma unroll
            for (int q = 0; q < 4; ++q) {
                float cy = cw[layer*8 + q*2 + 0];
                float sy = sw[layer*8 + q*2 + 0];
                float cz = cw[layer*8 + q*2 + 1];
                float sz = sw[layer*8 + q*2 + 1];
                int st = 8 >> q;
                #pragma unroll
                for (int i = 0; i < 16; ++i) {
                    if (i & st) continue;
                    int j = i | st;
                    float r0 = re[i], r1 = re[j], i0 = im[i], i1 = im[j];
                    float nr0 = cy*r0 - sy*r1;
                    float nr1 = sy*r0 + cy*r1;
                    float ni0 = cy*i0 - sy*i1;
                    float ni1 = sy*i0 + cy*i1;
                    re[i] = nr0*cz + ni0*sz;
                    im[i] = ni0*cz - nr0*sz;
                    re[j] = nr1*cz - ni1*sz;
                    im[j] = ni1*cz + nr1*sz;
                }
            }
            #pragma unroll
            for (int q = 0; q < 4; ++q) {
                int cb = 8 >> q;
                int tb = 8 >> ((q + 1) & 3);
                #pragma unroll
                for (int i = 0; i < 16; ++i) {
                    if ((i & cb) && !(i & tb)) {
                        int j = i | tb;
                        float tr = re[i]; re[i] = re[j]; re[j] = tr;
                        float ti = im[i]; im[i] = im[j]; im[j] = ti;
                    }
                }
            }
        }
        #pragma unroll
        for (int i = 0; i < 16; ++i) { Ur[i][col] = re[i]; Ui[i][col] = im[i]; }
    }
    __syncthreads();

    for (int e = tid; e < 1024; e += 256) {
        int q = e >> 8, j = (e >> 4) & 15, k = e & 15;
        float sum = 0.f;
        for (int i = 0; i < 16; ++i) {
            float t = Ur[i][j]*Ur[i][k] + Ui[i][j]*Ui[i][k];
            sum += (i & (8 >> q)) ? -t : t;
        }
        A[q][j][k] = sum;
    }
    __syncthreads();

    if (tid < 100) {
        const int pu[10] = {0,0,0,0,1,1,1,2,2,3};
        const int pv[10] = {0,1,2,3,1,2,3,2,3,3};
        int pi = tid / 10, qi = tid % 10;
        int u = pu[pi], v = pv[pi], r = pu[qi], sI = pv[qi];
        int a1s[2] = {u, v}, a2s[2] = {v, u};
        int b1s[2] = {r, sI}, b2s[2] = {sI, r};
        int na = (u == v) ? 1 : 2;
        int nb = (r == sI) ? 1 : 2;
        float acc[4] = {0.f, 0.f, 0.f, 0.f};
        for (int ia = 0; ia < na; ++ia)
            for (int ib = 0; ib < nb; ++ib) {
                int j = a1s[ia]*4 + b1s[ib];
                int k = a2s[ia]*4 + b2s[ib];
                #pragma unroll
                for (int q = 0; q < 4; ++q) acc[q] += A[q][j][k];
            }
        C4g[tid] = float4{acc[0], acc[1], acc[2], acc[3]};
    }
}

__global__ __launch_bounds__(256) void qmain(
    const float* __restrict__ x,
    const float4* __restrict__ C4g,  // uniform indices -> s_load_dwordx4
    float* __restrict__ out,
    int B)
{
    const int s0 = blockIdx.x * 256 + threadIdx.x;

    float4 xv = (s0 < B) ? reinterpret_cast<const float4*>(x)[s0]
                         : float4{0.f, 0.f, 0.f, 0.f};

    const int pu[10] = {0,0,0,0,1,1,1,2,2,3};
    const int pv[10] = {0,1,2,3,1,2,3,2,3,3};

    float P[10], Q[10];
    {
        float xs[4] = {xv.x, xv.y, xv.z, xv.w};
        float c[4], s[4];
        #pragma unroll
        for (int q = 0; q < 4; ++q) {
            // tanh(x) = 1 - 2/(e^{2x}+1); fast-math err ~1e-6 vs 2e-2 threshold
            float e = __expf(2.f * xs[q]);
            float t = 1.f - __fdividef(2.f, e + 1.f);
            __sincosf(t * HALF_PI_F, &s[q], &c[q]);
        }
        float a4[4] = {c[0]*c[1], c[0]*s[1], s[0]*c[1], s[0]*s[1]};
        float b4[4] = {c[2]*c[3], c[2]*s[3], s[2]*c[3], s[2]*s[3]};
        #pragma unroll
        for (int i2 = 0; i2 < 10; ++i2) {
            P[i2] = a4[pu[i2]] * a4[pv[i2]];
            Q[i2] = b4[pu[i2]] * b4[pv[i2]];
        }
    }

    // z_q = sum_pi P[pi] * (sum_qi C4[pi][qi][q] * Q[qi]) — pure scalar FMA,
    // coefficients arrive as SGPRs from merged s_load_dwordx4.
    float z0 = 0.f, z1 = 0.f, z2 = 0.f, z3 = 0.f;
    #pragma unroll
    for (int pi = 0; pi < 10; ++pi) {
        float t0 = 0.f, t1 = 0.f, t2 = 0.f, t3 = 0.f;
        #pragma unroll
        for (int qi = 0; qi < 10; ++qi) {
            float4 cv = C4g[pi*10 + qi];
            float qv = Q[qi];
            t0 = fmaf(cv.x, qv, t0);
            t1 = fmaf(cv.y, qv, t1);
            t2 = fmaf(cv.z, qv, t2);
            t3 = fmaf(cv.w, qv, t3);
        }
        float pvf = P[pi];
        z0 = fmaf(pvf, t0, z0);
        z1 = fmaf(pvf, t1, z1);
        z2 = fmaf(pvf, t2, z2);
        z3 = fmaf(pvf, t3, z3);
    }

    if (s0 < B)
        reinterpret_cast<float4*>(out)[s0] = float4{z0, z1, z2, z3};
}

extern "C" void kernel_launch(void* const* d_in, const int* in_sizes, int n_in,
                              void* d_out, int out_size, void* d_ws, size_t ws_size,
                              hipStream_t stream) {
    const float* x = (const float*)d_in[0];
    const float* w = (const float*)d_in[1];
    float* out = (float*)d_out;
    float4* C4g = (float4*)d_ws;  // 100 float4 = 1600 B
    int B = in_sizes[0] / 4;

    build_C4<<<1, 256, 0, stream>>>(w, C4g);
    int grid = (B + 255) / 256;  // 1 sample/thread, 256 threads/block
    qmain<<<grid, 256, 0, stream>>>(x, C4g, out, B);
}